// Round 13
// baseline (95.576 us; speedup 1.0000x reference)
//
#include <hip/hip_runtime.h>
#include <hip/hip_bf16.h>
#include <stdint.h>

// RadianceNetwork: 256 independent channel MLPs, B=64.
//   x  = concat(ue[3], view[3], feat[128], nid[1])  -> [64, 135]
//   h1 = relu(x @ W1[c] + b1[c])                    -> [64, 256]
//   h2 = relu(h1 @ W2[c] + b2[c])                   -> [64, 256]
//   o  = h2 @ W3[c] + b3[c]                         -> [64, 816]
// OUTPUT: real components only, fp32 [64][256][408] (R0-R5 forensics).
//
// R5-R12 invariant: effective load-queue depth ~1/wave (delivered BW stuck
// at 3.4 TB/s, all pipes <10%). R12's VGPR=60 proved hipcc SANK the
// prefetch loads to their use (legal: no fence), killing the pipeline.
// R13: direct-to-register W streaming with a FLAT (nt,kt) software pipeline,
// lookahead LA=4 tiles (32 loads in flight/wave), pinned with
// __builtin_amdgcn_sched_barrier(0) after every issue group so loads cannot
// sink. Register sets indexed by tile kt (static after unroll; window<=5<KT
// so no aliasing). Lookahead crosses n-tile seams -> one cold start/layer.
// LDS: h1 32K + {x|h2} 32K = 64KB static. Grid 256 (1 block/CU), 8 waves.

#define NCH    256
#define BATCH  64
#define MT     4      // 16-row m-tiles (full batch)
#define IN_K   135
#define HID    256
#define OUTN   816
#define OUTS   408    // stored real components per (m, c)
#define XPITCHB 336   // bytes per x row (168 bf16; zero-padded k in [135,168))
#define HROWB   512   // bytes per h row (256 bf16, swizzled)
#define NWAVES 8
#define BLOCK  512
#define LA     4      // lookahead tiles in flight per wave

typedef __bf16 bf16x8 __attribute__((ext_vector_type(8)));
typedef float  f32x4  __attribute__((ext_vector_type(4)));

// One layer, barrier-free, register-streamed W.
// MFMA 16x16x32 bf16 (layouts HW-verified, m89):
//   A: row m=lane&15, k=(lane>>4)*8+i  (ds_read_b128 from shared h/x LDS)
//   B: col n=lane&15, k=(lane>>4)*8+i  (8 strided global dwords -> cvt)
//   D: col n=lane&15, row m=(lane>>4)*4+r
template<int K, int KT, int NSRC, int NTT, bool ASWZ, bool RELU>
__device__ __forceinline__ void layer_stream(
    const char*  __restrict__ A,     // LDS activations (x or swizzled h)
    const float* __restrict__ Wg,    // [K][NSRC] weights, channel base
    const float* __restrict__ bg,    // bias, channel base
    char*        __restrict__ Hout,  // LDS out (RELU), swizzled pitch 512B
    float*       __restrict__ Gout,  // global out base (+c*OUTS)
    unsigned long long out_sz,
    int wave, int lane)
{
  const int col = lane & 15;
  const int g   = lane >> 4;
  const float* wb = Wg + col;        // + k*NSRC + nt*16 per load

  float ld[KT][8];                   // set = tile's kt; static idx after unroll

  // Issue the 8 strided loads of tile (nt2, kt2) into set kt2.
  // nt2 is wave-uniform -> scalar branch. K-tail (L1) predicated to 0
  // (matches zero-padded A rows).
  auto issue = [&](int nt2, int kt2) {
    if (nt2 < NTT) {
#pragma unroll
      for (int i = 0; i < 8; ++i) {
        const int k = kt2 * 32 + g * 8 + i;
        if ((K % 32 == 0) || (k < K))
          ld[kt2][i] = wb[(size_t)k * NSRC + nt2 * 16];
        else
          ld[kt2][i] = 0.0f;
      }
    }
  };

  // prologue: first LA tiles of this wave's first n-tile (LA <= KT always)
#pragma unroll
  for (int p = 0; p < LA; ++p) issue(wave, p);
  __builtin_amdgcn_sched_barrier(0);   // pin: loads may not sink

  for (int nt = wave; nt < NTT; nt += NWAVES) {
    f32x4 acc[MT] = {};
#pragma unroll
    for (int kt = 0; kt < KT; ++kt) {
      // issue tile at flat position +LA (crosses into next n-tile)
      if (kt + LA < KT) issue(nt, kt + LA);
      else              issue(nt + NWAVES, kt + LA - KT);
      __builtin_amdgcn_sched_barrier(0);  // pin: loads may not sink

      // consume set kt (compiler emits counted vmcnt for exactly this set)
      bf16x8 bfrag;
#pragma unroll
      for (int i = 0; i < 8; ++i) bfrag[i] = (__bf16)ld[kt][i];

      const int kb = kt * 32 + g * 8;
#pragma unroll
      for (int mt = 0; mt < MT; ++mt) {
        const int m = mt * 16 + col;
        const uint32_t ab = ASWZ
            ? (uint32_t)m * HROWB + (((uint32_t)(kb * 2)) ^ (((uint32_t)m & 7u) << 4))
            : (uint32_t)m * XPITCHB + (uint32_t)(kb * 2);
        const bf16x8 afrag = *(const bf16x8*)(A + ab);
        acc[mt] = __builtin_amdgcn_mfma_f32_16x16x32_bf16(afrag, bfrag, acc[mt], 0, 0, 0);
      }
    }

    // epilogue: bias (+relu->LDS | even-col fp32->global)
    const int n = nt * 16 + col;
    const float bias = bg[n];
#pragma unroll
    for (int mt = 0; mt < MT; ++mt) {
#pragma unroll
      for (int r = 0; r < 4; ++r) {
        float v = acc[mt][r] + bias;
        const int m = mt * 16 + g * 4 + r;
        if (RELU) {
          v = v > 0.f ? v : 0.f;
          *(__bf16*)(Hout + (uint32_t)m * HROWB +
                     (((uint32_t)(n * 2)) ^ (((uint32_t)m & 7u) << 4))) = (__bf16)v;
        } else if ((n & 1) == 0) {           // real component only
          const unsigned long long oi =
              (unsigned long long)m * (NCH * OUTS) + (unsigned long long)(n >> 1);
          if (oi < out_sz) Gout[oi] = v;
        }
      }
    }
  }
}

__global__ __launch_bounds__(BLOCK) void radiance_mlp_kernel(
    const float* __restrict__ ue,   const float* __restrict__ view,
    const float* __restrict__ feat, const int*   __restrict__ ids,
    const float* __restrict__ W1, const float* __restrict__ b1,
    const float* __restrict__ W2, const float* __restrict__ b2,
    const float* __restrict__ W3, const float* __restrict__ b3,
    float* __restrict__ out, unsigned long long out_sz)
{
  __shared__ __attribute__((aligned(16))) char buf0[BATCH * HROWB]; // h1: 32 KB
  __shared__ __attribute__((aligned(16))) char buf1[BATCH * HROWB]; // x / h2: 32 KB

  const int c    = blockIdx.x;        // one full-batch block per channel
  const int tid  = threadIdx.x;
  const int wave = tid >> 6;
  const int lane = tid & 63;

  // Stage input x -> bf16 in buf1 (pitch 336B), zero-pad k in [135,168).
  for (int idx = tid; idx < BATCH * (XPITCHB / 2); idx += BLOCK) {
    const int m = idx / (XPITCHB / 2);
    const int k = idx - m * (XPITCHB / 2);
    float v = 0.0f;
    if (k < 3)         v = ue[m * 3 + k];
    else if (k < 6)    v = view[m * 3 + (k - 3)];
    else if (k < 134)  v = feat[m * 128 + (k - 6)];
    else if (k == 134) v = ((float)ids[m] - 1.0f) * (1.0f / 63.0f);
    *(__bf16*)(buf1 + (uint32_t)m * XPITCHB + 2u * (uint32_t)k) = (__bf16)v;
  }
  __syncthreads();

  // L1: x(buf1) -> h1(buf0).  K=135 (5 k-tiles, tail predicated), N=256.
  layer_stream<IN_K, 5, HID, 16, false, true>(
      buf1, W1 + (size_t)c * IN_K * HID, b1 + (size_t)c * HID,
      buf0, nullptr, 0, wave, lane);
  __syncthreads();

  // L2: h1(buf0) -> h2(buf1).  K=256, N=256.
  layer_stream<HID, 8, HID, 16, true, true>(
      buf0, W2 + (size_t)c * HID * HID, b2 + (size_t)c * HID,
      buf1, nullptr, 0, wave, lane);
  __syncthreads();

  // L3: h2(buf1) -> out.  K=256, N=816 (51 n-tiles round-robin over waves).
  layer_stream<HID, 8, OUTN, 51, true, false>(
      buf1, W3 + (size_t)c * HID * OUTN, b3 + (size_t)c * OUTN,
      nullptr, out + (size_t)c * OUTS, out_sz, wave, lane);
}

extern "C" void kernel_launch(void* const* d_in, const int* in_sizes, int n_in,
                              void* d_out, int out_size, void* d_ws, size_t ws_size,
                              hipStream_t stream) {
  const float* ue   = (const float*)d_in[0];
  const float* view = (const float*)d_in[1];
  const float* feat = (const float*)d_in[2];
  const int*   ids  = (const int*)d_in[3];
  const float* W1   = (const float*)d_in[4];
  const float* b1   = (const float*)d_in[5];
  const float* W2   = (const float*)d_in[6];
  const float* b2   = (const float*)d_in[7];
  const float* W3   = (const float*)d_in[8];
  const float* b3   = (const float*)d_in[9];
  float* out = (float*)d_out;

  hipLaunchKernelGGL(radiance_mlp_kernel, dim3(NCH), dim3(BLOCK), 0, stream,
                     ue, view, feat, ids, W1, b1, W2, b2, W3, b3,
                     out, (unsigned long long)out_size);
}

// Round 15
// 89.678 us; speedup vs baseline: 1.0658x; 1.0658x over previous
//
#include <hip/hip_runtime.h>
#include <hip/hip_bf16.h>
#include <stdint.h>

// RadianceNetwork: 256 independent channel MLPs, B=64.
//   x  = concat(ue[3], view[3], feat[128], nid[1])  -> [64, 135]
//   h1 = relu(x @ W1[c] + b1[c])                    -> [64, 256]
//   h2 = relu(h1 @ W2[c] + b2[c])                   -> [64, 256]
//   o  = h2 @ W3[c] + b3[c]                         -> [64, 816]
// OUTPUT: real components only, fp32 [64][256][408] (R0-R5 forensics).
//
// R14 bug: steady-state s_waitcnt vmcnt(4) stops protecting the consumed
// tile once issues stop (last LOOKA iterations + layer seams) -> read-
// before-DMA-lands races -> absmax 0.51. R15: issue BEFORE wait and wait
// vmcnt(2*min(3, TOT-1-tau)): 6 steady / 4,2,0 drain. vmcnt(0) at layer end
// also kills cross-layer slot leakage. Everything else = R14:
// W streamed via global_load_lds DMA (zero data VGPRs; depth in the vmcnt
// queue, compiler can't sink/spill it). Wave-private 4-slot LDS ring
// (2KB = 32kx16n fp32 tile, 2 DMA instrs x 64 lanes x 16B). No barriers
// inside layers. B-frag = 8x ds_read_b32 + cvt.
// LDS: h1 32K + {x|h2} 32K + rings 64K = 128KB dynamic. Grid 256, 8 waves.

#define NCH    256
#define BATCH  64
#define MT     4      // 16-row m-tiles (full batch)
#define IN_K   135
#define HID    256
#define OUTN   816
#define OUTS   408    // stored real components per (m, c)
#define XPITCHB 336   // bytes per x row (168 bf16; zero-padded k in [135,168))
#define HROWB   512   // bytes per h row (256 bf16, swizzled)
#define NWAVES 8
#define BLOCK  512
#define LOOKA  3      // W tiles in flight per wave (beyond the consumed one)
#define RING   4      // LDS ring slots per wave (2KB each)
#define SMEM_BYTES (128 * 1024)

typedef __bf16 bf16x8 __attribute__((ext_vector_type(8)));
typedef float  f32x4  __attribute__((ext_vector_type(4)));
typedef const __attribute__((address_space(1))) void* gas_t;
typedef __attribute__((address_space(3))) void*       las_t;

// One layer, barrier-free, DMA-streamed W.
// MFMA 16x16x32 bf16 (layouts HW-verified, m89):
//   A: row m=lane&15, k=(lane>>4)*8+i  (ds_read_b128 from shared h/x LDS)
//   B: col n=lane&15, k=(lane>>4)*8+i  (ds_read_b32 from ring slot + cvt)
//   D: col n=lane&15, row m=(lane>>4)*4+r
// Ring slot (DMA-written, linear): fp32 [k 0..31][n 0..15], 64B per k-row;
// DMA j, lane l covers k=j*16+(l>>2), n-quad (l&3)*4  (dest = base+l*16).
template<int K, int KT, int NSRC, int NTT, bool ASWZ, bool RELU>
__device__ __forceinline__ void layer_dma(
    const char*  __restrict__ A,     // LDS activations (x or swizzled h)
    const float* __restrict__ Wg,    // [K][NSRC] weights, channel base
    const float* __restrict__ bg,    // bias, channel base
    char*        __restrict__ Hout,  // LDS out (RELU), swizzled pitch 512B
    float*       __restrict__ Gout,  // global out base (+c*OUTS)
    unsigned long long out_sz,
    char* __restrict__ ring,         // wave-private RING*2048 bytes
    int wave, int lane)
{
  const int col = lane & 15;
  const int g   = lane >> 4;
  const int kl  = lane >> 2;         // DMA k-row within 16-row half
  const int nq  = (lane & 3) * 4;    // DMA n-quad

  const int ACNT = (NTT - wave + NWAVES - 1) / NWAVES;  // n-tiles this wave
  const int TOT  = ACNT * KT;                           // flat tile count

  auto issue = [&](int tau2) {
    if (tau2 < TOT) {
      const int a  = tau2 / KT;
      const int kt = tau2 - a * KT;
      const int nt = wave + a * NWAVES;
      char* slot = ring + (tau2 & (RING - 1)) * 2048;
#pragma unroll
      for (int j = 0; j < 2; ++j) {
        int k = kt * 32 + j * 16 + kl;
        if (K % 32 != 0) k = (k < K) ? k : (K - 1);  // finite clamp; A rows zero there
        const float* src = Wg + (size_t)k * NSRC + nt * 16 + nq;
        __builtin_amdgcn_global_load_lds((gas_t)src, (las_t)(slot + j * 1024),
                                         16, 0, 0);
      }
    }
  };

  // prologue: LOOKA tiles in flight (2*LOOKA DMA instrs)
  issue(0); issue(1); issue(2);

  int tau = 0;
  for (int a = 0; a < ACNT; ++a) {
    const int nt = wave + a * NWAVES;
    f32x4 acc[MT] = {};
#pragma unroll
    for (int kt = 0; kt < KT; ++kt, ++tau) {
      issue(tau + LOOKA);   // refill first (slot of tile tau-1, read last iter)
      // graduated wait: newest outstanding = tiles tau+1..min(tau+3,TOT-1)
      // = 2*min(3, rem) ops; anything older (incl. tile tau) has landed.
      const int rem = TOT - 1 - tau;   // wave-uniform -> scalar branch
      if      (rem >= 3) asm volatile("s_waitcnt vmcnt(6)" ::: "memory");
      else if (rem == 2) asm volatile("s_waitcnt vmcnt(4)" ::: "memory");
      else if (rem == 1) asm volatile("s_waitcnt vmcnt(2)" ::: "memory");
      else               asm volatile("s_waitcnt vmcnt(0)" ::: "memory");

      const char* slot = ring + (tau & (RING - 1)) * 2048;
      bf16x8 bfrag;
#pragma unroll
      for (int i = 0; i < 8; ++i) {
        const float w = *(const float*)(slot + (uint32_t)((g * 8 + i) * 16 + col) * 4u);
        bfrag[i] = (__bf16)w;
      }
      const int kb = kt * 32 + g * 8;
#pragma unroll
      for (int mt = 0; mt < MT; ++mt) {
        const int m = mt * 16 + col;
        const uint32_t ab = ASWZ
            ? (uint32_t)m * HROWB + (((uint32_t)(kb * 2)) ^ (((uint32_t)m & 7u) << 4))
            : (uint32_t)m * XPITCHB + (uint32_t)(kb * 2);
        const bf16x8 afrag = *(const bf16x8*)(A + ab);
        acc[mt] = __builtin_amdgcn_mfma_f32_16x16x32_bf16(afrag, bfrag, acc[mt], 0, 0, 0);
      }
    }

    // epilogue: bias (+relu->LDS | even-col fp32->global)
    const int n = nt * 16 + col;
    const float bias = bg[n];
#pragma unroll
    for (int mt = 0; mt < MT; ++mt) {
#pragma unroll
      for (int r = 0; r < 4; ++r) {
        float v = acc[mt][r] + bias;
        const int m = mt * 16 + g * 4 + r;
        if (RELU) {
          v = v > 0.f ? v : 0.f;
          *(__bf16*)(Hout + (uint32_t)m * HROWB +
                     (((uint32_t)(n * 2)) ^ (((uint32_t)m & 7u) << 4))) = (__bf16)v;
        } else if ((n & 1) == 0) {           // real component only
          const unsigned long long oi =
              (unsigned long long)m * (NCH * OUTS) + (unsigned long long)(n >> 1);
          if (oi < out_sz) Gout[oi] = v;
        }
      }
    }
  }
}

__global__ __launch_bounds__(BLOCK) void radiance_mlp_kernel(
    const float* __restrict__ ue,   const float* __restrict__ view,
    const float* __restrict__ feat, const int*   __restrict__ ids,
    const float* __restrict__ W1, const float* __restrict__ b1,
    const float* __restrict__ W2, const float* __restrict__ b2,
    const float* __restrict__ W3, const float* __restrict__ b3,
    float* __restrict__ out, unsigned long long out_sz)
{
  extern __shared__ __attribute__((aligned(16))) char smem[];
  char* buf0 = smem;                 // h1: 32 KB (swizzled pitch 512B)
  char* buf1 = smem + 32768;         // x (pitch 336B) then h2: 32 KB
  char* ring = smem + 65536 + (threadIdx.x >> 6) * (RING * 2048);

  const int c    = blockIdx.x;       // one full-batch block per channel
  const int tid  = threadIdx.x;
  const int wave = tid >> 6;
  const int lane = tid & 63;

  // Stage input x -> bf16 in buf1 (pitch 336B), zero-pad k in [135,168).
  for (int idx = tid; idx < BATCH * (XPITCHB / 2); idx += BLOCK) {
    const int m = idx / (XPITCHB / 2);
    const int k = idx - m * (XPITCHB / 2);
    float v = 0.0f;
    if (k < 3)         v = ue[m * 3 + k];
    else if (k < 6)    v = view[m * 3 + (k - 3)];
    else if (k < 134)  v = feat[m * 128 + (k - 6)];
    else if (k == 134) v = ((float)ids[m] - 1.0f) * (1.0f / 63.0f);
    *(__bf16*)(buf1 + (uint32_t)m * XPITCHB + 2u * (uint32_t)k) = (__bf16)v;
  }
  __syncthreads();

  // L1: x(buf1) -> h1(buf0).  K=135 (5 k-tiles, tail clamped), N=256.
  layer_dma<IN_K, 5, HID, 16, false, true>(
      buf1, W1 + (size_t)c * IN_K * HID, b1 + (size_t)c * HID,
      buf0, nullptr, 0, ring, wave, lane);
  __syncthreads();

  // L2: h1(buf0) -> h2(buf1).  K=256, N=256.
  layer_dma<HID, 8, HID, 16, true, true>(
      buf0, W2 + (size_t)c * HID * HID, b2 + (size_t)c * HID,
      buf1, nullptr, 0, ring, wave, lane);
  __syncthreads();

  // L3: h2(buf1) -> out.  K=256, N=816 (51 n-tiles round-robin over waves).
  layer_dma<HID, 8, OUTN, 51, true, false>(
      buf1, W3 + (size_t)c * HID * OUTN, b3 + (size_t)c * OUTN,
      nullptr, out + (size_t)c * OUTS, out_sz, ring, wave, lane);
}

extern "C" void kernel_launch(void* const* d_in, const int* in_sizes, int n_in,
                              void* d_out, int out_size, void* d_ws, size_t ws_size,
                              hipStream_t stream) {
  const float* ue   = (const float*)d_in[0];
  const float* view = (const float*)d_in[1];
  const float* feat = (const float*)d_in[2];
  const int*   ids  = (const int*)d_in[3];
  const float* W1   = (const float*)d_in[4];
  const float* b1   = (const float*)d_in[5];
  const float* W2   = (const float*)d_in[6];
  const float* b2   = (const float*)d_in[7];
  const float* W3   = (const float*)d_in[8];
  const float* b3   = (const float*)d_in[9];
  float* out = (float*)d_out;

  // Host-side attribute set (not a stream op; graph-capture-safe, idempotent).
  hipFuncSetAttribute(reinterpret_cast<const void*>(radiance_mlp_kernel),
                      hipFuncAttributeMaxDynamicSharedMemorySize, SMEM_BYTES);

  hipLaunchKernelGGL(radiance_mlp_kernel, dim3(NCH), dim3(BLOCK), SMEM_BYTES,
                     stream, ue, view, feat, ids, W1, b1, W2, b2, W3, b3,
                     out, (unsigned long long)out_size);
}

// Round 16
// 84.554 us; speedup vs baseline: 1.1304x; 1.0606x over previous
//
#include <hip/hip_runtime.h>
#include <hip/hip_bf16.h>
#include <stdint.h>

// RadianceNetwork: 256 independent channel MLPs, B=64.
//   x  = concat(ue[3], view[3], feat[128], nid[1])  -> [64, 135]
//   h1 = relu(x @ W1[c] + b1[c])                    -> [64, 256]
//   h2 = relu(h1 @ W2[c] + b2[c])                   -> [64, 256]
//   o  = h2 @ W3[c] + b3[c]                         -> [64, 816]
// OUTPUT: real components only, fp32 [64][256][408] (R0-R5 forensics).
//
// R16 = m201-style schedule: 16 waves (1024 thr), block-cooperative W
// staging via global_load_lds into a 4-slot ring of 32k x 128n fp32 tiles
// (16 KB each), RAW s_barrier + graduated counted vmcnt (2/1/0) so 2 tiles
// stay in flight ACROSS barriers (__syncthreads would drain vmcnt(0) - the
// R9/R11 mistake). Each wave's DMA = ONE dwordx4 instr = 2 contiguous 512B
// row-slices (8 whole cache lines; R15's wave-private slices were 16
// scattered 64B segments). One barrier/step; slot reuse proven safe
// (issue(t+2) overwrites tile t-2, computed before barrier(t-1)).
// Wave w: n-tile w&7 (16 cols), m-half w>>3 (32 rows), MT=2.
// L1/L2: 2 chunks of 128 cols; L3: 6x128 + 48.
// LDS: h1 32K + {x|h2} 32K + ring 64K = 128 KB dynamic. Grid 256.

#define NCH    256
#define BATCH  64
#define IN_K   135
#define HID    256
#define OUTN   816
#define OUTS   408    // stored real components per (m, c)
#define XPITCHB 336   // bytes per x row (168 bf16; zero-padded k in [135,168))
#define HROWB   512   // bytes per h row (256 bf16, swizzled)
#define NWAVES 16
#define BLOCK  1024
#define SLOTB  16384  // 32 k-rows x 128 n-cols fp32
#define SMEM_BYTES (128 * 1024)

typedef __bf16 bf16x8 __attribute__((ext_vector_type(8)));
typedef float  f32x4  __attribute__((ext_vector_type(4)));
typedef const __attribute__((address_space(1))) void* gas_t;
typedef __attribute__((address_space(3))) void*       las_t;

// One 128(or 48)-col chunk of one layer, k accumulated over KT 32-tiles.
// MFMA 16x16x32 bf16 (layouts HW-verified, m89):
//   A: row m=lane&15, k=(lane>>4)*8+i  (ds_read_b128 from shared h/x LDS)
//   B: col n=lane&15, same k           (ds_read_b32 from ring slot + cvt)
//   D: col n=lane&15, row m=(lane>>4)*4+r
// Ring slot (DMA, linear): fp32 [k 0..31][n 0..127]; wave w's 1 instr
// covers rows 2w,2w+1 (dest = slot + w*1024 + lane*16; src per-lane).
template<int K, int KT, int NSRC, int NCW, bool ASWZ, bool RELU>
__device__ __forceinline__ void chunk_pipe(
    const char*  __restrict__ A,     // LDS activations (x or swizzled h)
    const float* __restrict__ Wg,    // [K][NSRC] weights, channel base
    const float* __restrict__ bg,    // bias, channel base
    char*        __restrict__ Hout,  // LDS out (RELU), swizzled pitch 512B
    float*       __restrict__ Gout,  // global out base (+c*OUTS)
    unsigned long long out_sz, int nc0,
    char* __restrict__ wslots,       // 4 x 16 KB ring
    int wave, int lane)
{
  const int col = lane & 15;
  const int g   = lane >> 4;
  const int nt  = wave & 7;          // n-tile within chunk
  const int mh  = wave >> 3;         // m-half (rows mh*32 .. +31)
  const bool active = (nt * 16) < NCW;

  // chunk entry: all waves done with previous chunk's slots & h-writes
  asm volatile("s_waitcnt lgkmcnt(0)" ::: "memory");
  asm volatile("s_barrier" ::: "memory");

  auto issue = [&](int t) {
    if (t < KT) {
      char* dst = wslots + (t & 3) * SLOTB + wave * 1024;
      const int r = 2 * wave + (lane >> 5);     // tile row 0..31
      int k = t * 32 + r;
      if (K % 32 != 0) k = (k < K) ? k : (K - 1);   // L1 tail: finite clamp
      size_t flat = (size_t)k * NSRC + nc0 + (size_t)(lane & 31) * 4;
      if (NCW < 128) {                          // 48-chunk: stay inside W[c]
        const size_t mx = (size_t)K * NSRC - 4;
        flat = (flat < mx) ? flat : mx;
      }
      __builtin_amdgcn_global_load_lds((gas_t)(Wg + flat), (las_t)dst, 16, 0, 0);
    }
  };

  issue(0); issue(1);                // 2 tiles in flight

  f32x4 acc[2] = {};

#pragma unroll
  for (int kt = 0; kt < KT; ++kt) {
    issue(kt + 2);                   // refill (slot of tile kt-2, long done)
    const int rem = KT - 1 - kt;     // graduated: newest min(2,rem) stay out
    if (rem >= 2)      asm volatile("s_waitcnt vmcnt(2)" ::: "memory");
    else if (rem == 1) asm volatile("s_waitcnt vmcnt(1)" ::: "memory");
    else               asm volatile("s_waitcnt vmcnt(0)" ::: "memory");
    asm volatile("s_barrier" ::: "memory");   // all waves' tile-kt landed

    if (active) {
      const char* slot = wslots + (kt & 3) * SLOTB;
      bf16x8 bfrag;
#pragma unroll
      for (int i = 0; i < 8; ++i) {
        const float w = *(const float*)(slot + (uint32_t)(g * 8 + i) * 512u +
                                        (uint32_t)(nt * 16 + col) * 4u);
        bfrag[i] = (__bf16)w;
      }
      const int kb = kt * 32 + g * 8;
#pragma unroll
      for (int mt = 0; mt < 2; ++mt) {
        const int m = mh * 32 + mt * 16 + col;
        const uint32_t ab = ASWZ
            ? (uint32_t)m * HROWB + (((uint32_t)(kb * 2)) ^ (((uint32_t)m & 7u) << 4))
            : (uint32_t)m * XPITCHB + (uint32_t)(kb * 2);
        const bf16x8 afrag = *(const bf16x8*)(A + ab);
        acc[mt] = __builtin_amdgcn_mfma_f32_16x16x32_bf16(afrag, bfrag, acc[mt], 0, 0, 0);
      }
    }
  }

  // epilogue: bias (+relu->LDS | even-col fp32->global)
  if (active) {
    const int n = nc0 + nt * 16 + col;
    const float bias = bg[n];
#pragma unroll
    for (int mt = 0; mt < 2; ++mt) {
#pragma unroll
      for (int r = 0; r < 4; ++r) {
        float v = acc[mt][r] + bias;
        const int m = mh * 32 + mt * 16 + g * 4 + r;
        if (RELU) {
          v = v > 0.f ? v : 0.f;
          *(__bf16*)(Hout + (uint32_t)m * HROWB +
                     (((uint32_t)(n * 2)) ^ (((uint32_t)m & 7u) << 4))) = (__bf16)v;
        } else if ((n & 1) == 0) {           // real component only
          const unsigned long long oi =
              (unsigned long long)m * (NCH * OUTS) + (unsigned long long)(n >> 1);
          if (oi < out_sz) Gout[oi] = v;
        }
      }
    }
  }
}

__global__ __launch_bounds__(BLOCK) void radiance_mlp_kernel(
    const float* __restrict__ ue,   const float* __restrict__ view,
    const float* __restrict__ feat, const int*   __restrict__ ids,
    const float* __restrict__ W1, const float* __restrict__ b1,
    const float* __restrict__ W2, const float* __restrict__ b2,
    const float* __restrict__ W3, const float* __restrict__ b3,
    float* __restrict__ out, unsigned long long out_sz)
{
  extern __shared__ __attribute__((aligned(16))) char smem[];
  char* buf0   = smem;               // h1: 32 KB (swizzled pitch 512B)
  char* buf1   = smem + 32768;       // x (pitch 336B) then h2: 32 KB
  char* wslots = smem + 65536;       // 4 x 16 KB W ring

  const int c    = blockIdx.x;       // one full-batch block per channel
  const int tid  = threadIdx.x;
  const int wave = tid >> 6;
  const int lane = tid & 63;

  // Stage input x -> bf16 in buf1 (pitch 336B), zero-pad k in [135,168).
  for (int idx = tid; idx < BATCH * (XPITCHB / 2); idx += BLOCK) {
    const int m = idx / (XPITCHB / 2);
    const int k = idx - m * (XPITCHB / 2);
    float v = 0.0f;
    if (k < 3)         v = ue[m * 3 + k];
    else if (k < 6)    v = view[m * 3 + (k - 3)];
    else if (k < 134)  v = feat[m * 128 + (k - 6)];
    else if (k == 134) v = ((float)ids[m] - 1.0f) * (1.0f / 63.0f);
    *(__bf16*)(buf1 + (uint32_t)m * XPITCHB + 2u * (uint32_t)k) = (__bf16)v;
  }
  __syncthreads();

  // L1: x(buf1) -> h1(buf0).  K=135 (5 k-tiles), N=256 in 2 chunks.
  const float* W1c = W1 + (size_t)c * IN_K * HID;
  const float* b1c = b1 + (size_t)c * HID;
  chunk_pipe<IN_K, 5, HID, 128, false, true>(buf1, W1c, b1c, buf0, nullptr, 0, 0,
                                             wslots, wave, lane);
  chunk_pipe<IN_K, 5, HID, 128, false, true>(buf1, W1c, b1c, buf0, nullptr, 0, 128,
                                             wslots, wave, lane);

  // L2: h1(buf0) -> h2(buf1).  K=256 (8 k-tiles), N=256 in 2 chunks.
  const float* W2c = W2 + (size_t)c * HID * HID;
  const float* b2c = b2 + (size_t)c * HID;
  chunk_pipe<HID, 8, HID, 128, true, true>(buf0, W2c, b2c, buf1, nullptr, 0, 0,
                                           wslots, wave, lane);
  chunk_pipe<HID, 8, HID, 128, true, true>(buf0, W2c, b2c, buf1, nullptr, 0, 128,
                                           wslots, wave, lane);

  // L3: h2(buf1) -> out.  K=256, N=816 = 6 x 128 + 48.
  const float* W3c = W3 + (size_t)c * HID * OUTN;
  const float* b3c = b3 + (size_t)c * OUTN;
  float* outc = out + (size_t)c * OUTS;
  for (int cc = 0; cc < 6; ++cc)
    chunk_pipe<HID, 8, OUTN, 128, true, false>(buf1, W3c, b3c, nullptr, outc,
                                               out_sz, cc * 128, wslots, wave, lane);
  chunk_pipe<HID, 8, OUTN, 48, true, false>(buf1, W3c, b3c, nullptr, outc,
                                            out_sz, 768, wslots, wave, lane);
}

extern "C" void kernel_launch(void* const* d_in, const int* in_sizes, int n_in,
                              void* d_out, int out_size, void* d_ws, size_t ws_size,
                              hipStream_t stream) {
  const float* ue   = (const float*)d_in[0];
  const float* view = (const float*)d_in[1];
  const float* feat = (const float*)d_in[2];
  const int*   ids  = (const int*)d_in[3];
  const float* W1   = (const float*)d_in[4];
  const float* b1   = (const float*)d_in[5];
  const float* W2   = (const float*)d_in[6];
  const float* b2   = (const float*)d_in[7];
  const float* W3   = (const float*)d_in[8];
  const float* b3   = (const float*)d_in[9];
  float* out = (float*)d_out;

  // Host-side attribute set (not a stream op; graph-capture-safe, idempotent).
  hipFuncSetAttribute(reinterpret_cast<const void*>(radiance_mlp_kernel),
                      hipFuncAttributeMaxDynamicSharedMemorySize, SMEM_BYTES);

  hipLaunchKernelGGL(radiance_mlp_kernel, dim3(NCH), dim3(BLOCK), SMEM_BYTES,
                     stream, ue, view, feat, ids, W1, b1, W2, b2, W3, b3,
                     out, (unsigned long long)out_size);
}

// Round 17
// 83.438 us; speedup vs baseline: 1.1455x; 1.0134x over previous
//
#include <hip/hip_runtime.h>
#include <hip/hip_bf16.h>
#include <stdint.h>

// RadianceNetwork: 256 independent channel MLPs, B=64.
//   x  = concat(ue[3], view[3], feat[128], nid[1])  -> [64, 135]
//   h1 = relu(x @ W1[c] + b1[c])                    -> [64, 256]
//   h2 = relu(h1 @ W2[c] + b2[c])                   -> [64, 256]
//   o  = h2 @ W3[c] + b3[c]                         -> [64, 816]
// OUTPUT: real components only, fp32 [64][256][408] (R0-R5 forensics).
//
// R16 = m201-style schedule: 16 waves (1024 thr), block-cooperative W
// staging via global_load_lds into a 4-slot ring of 32k x 128n fp32 tiles
// (16 KB each), RAW s_barrier + graduated counted vmcnt (2/1/0) so 2 tiles
// stay in flight ACROSS barriers (__syncthreads would drain vmcnt(0) - the
// R9/R11 mistake). Each wave's DMA = ONE dwordx4 instr = 2 contiguous 512B
// row-slices (8 whole cache lines; R15's wave-private slices were 16
// scattered 64B segments). One barrier/step; slot reuse proven safe
// (issue(t+2) overwrites tile t-2, computed before barrier(t-1)).
// Wave w: n-tile w&7 (16 cols), m-half w>>3 (32 rows), MT=2.
// L1/L2: 2 chunks of 128 cols; L3: 6x128 + 48.
// LDS: h1 32K + {x|h2} 32K + ring 64K = 128 KB dynamic. Grid 256.

#define NCH    256
#define BATCH  64
#define IN_K   135
#define HID    256
#define OUTN   816
#define OUTS   408    // stored real components per (m, c)
#define XPITCHB 336   // bytes per x row (168 bf16; zero-padded k in [135,168))
#define HROWB   512   // bytes per h row (256 bf16, swizzled)
#define NWAVES 16
#define BLOCK  1024
#define SLOTB  16384  // 32 k-rows x 128 n-cols fp32
#define SMEM_BYTES (128 * 1024)

typedef __bf16 bf16x8 __attribute__((ext_vector_type(8)));
typedef float  f32x4  __attribute__((ext_vector_type(4)));
typedef const __attribute__((address_space(1))) void* gas_t;
typedef __attribute__((address_space(3))) void*       las_t;

// One 128(or 48)-col chunk of one layer, k accumulated over KT 32-tiles.
// MFMA 16x16x32 bf16 (layouts HW-verified, m89):
//   A: row m=lane&15, k=(lane>>4)*8+i  (ds_read_b128 from shared h/x LDS)
//   B: col n=lane&15, same k           (ds_read_b32 from ring slot + cvt)
//   D: col n=lane&15, row m=(lane>>4)*4+r
// Ring slot (DMA, linear): fp32 [k 0..31][n 0..127]; wave w's 1 instr
// covers rows 2w,2w+1 (dest = slot + w*1024 + lane*16; src per-lane).
template<int K, int KT, int NSRC, int NCW, bool ASWZ, bool RELU>
__device__ __forceinline__ void chunk_pipe(
    const char*  __restrict__ A,     // LDS activations (x or swizzled h)
    const float* __restrict__ Wg,    // [K][NSRC] weights, channel base
    const float* __restrict__ bg,    // bias, channel base
    char*        __restrict__ Hout,  // LDS out (RELU), swizzled pitch 512B
    float*       __restrict__ Gout,  // global out base (+c*OUTS)
    unsigned long long out_sz, int nc0,
    char* __restrict__ wslots,       // 4 x 16 KB ring
    int wave, int lane)
{
  const int col = lane & 15;
  const int g   = lane >> 4;
  const int nt  = wave & 7;          // n-tile within chunk
  const int mh  = wave >> 3;         // m-half (rows mh*32 .. +31)
  const bool active = (nt * 16) < NCW;

  // chunk entry: all waves done with previous chunk's slots & h-writes
  asm volatile("s_waitcnt lgkmcnt(0)" ::: "memory");
  asm volatile("s_barrier" ::: "memory");

  auto issue = [&](int t) {
    if (t < KT) {
      char* dst = wslots + (t & 3) * SLOTB + wave * 1024;
      const int r = 2 * wave + (lane >> 5);     // tile row 0..31
      int k = t * 32 + r;
      if (K % 32 != 0) k = (k < K) ? k : (K - 1);   // L1 tail: finite clamp
      size_t flat = (size_t)k * NSRC + nc0 + (size_t)(lane & 31) * 4;
      if (NCW < 128) {                          // 48-chunk: stay inside W[c]
        const size_t mx = (size_t)K * NSRC - 4;
        flat = (flat < mx) ? flat : mx;
      }
      __builtin_amdgcn_global_load_lds((gas_t)(Wg + flat), (las_t)dst, 16, 0, 0);
    }
  };

  issue(0); issue(1);                // 2 tiles in flight

  f32x4 acc[2] = {};

#pragma unroll
  for (int kt = 0; kt < KT; ++kt) {
    issue(kt + 2);                   // refill (slot of tile kt-2, long done)
    const int rem = KT - 1 - kt;     // graduated: newest min(2,rem) stay out
    if (rem >= 2)      asm volatile("s_waitcnt vmcnt(2)" ::: "memory");
    else if (rem == 1) asm volatile("s_waitcnt vmcnt(1)" ::: "memory");
    else               asm volatile("s_waitcnt vmcnt(0)" ::: "memory");
    asm volatile("s_barrier" ::: "memory");   // all waves' tile-kt landed

    if (active) {
      const char* slot = wslots + (kt & 3) * SLOTB;
      bf16x8 bfrag;
#pragma unroll
      for (int i = 0; i < 8; ++i) {
        const float w = *(const float*)(slot + (uint32_t)(g * 8 + i) * 512u +
                                        (uint32_t)(nt * 16 + col) * 4u);
        bfrag[i] = (__bf16)w;
      }
      const int kb = kt * 32 + g * 8;
#pragma unroll
      for (int mt = 0; mt < 2; ++mt) {
        const int m = mh * 32 + mt * 16 + col;
        const uint32_t ab = ASWZ
            ? (uint32_t)m * HROWB + (((uint32_t)(kb * 2)) ^ (((uint32_t)m & 7u) << 4))
            : (uint32_t)m * XPITCHB + (uint32_t)(kb * 2);
        const bf16x8 afrag = *(const bf16x8*)(A + ab);
        acc[mt] = __builtin_amdgcn_mfma_f32_16x16x32_bf16(afrag, bfrag, acc[mt], 0, 0, 0);
      }
    }
  }

  // epilogue: bias (+relu->LDS | even-col fp32->global)
  if (active) {
    const int n = nc0 + nt * 16 + col;
    const float bias = bg[n];
#pragma unroll
    for (int mt = 0; mt < 2; ++mt) {
#pragma unroll
      for (int r = 0; r < 4; ++r) {
        float v = acc[mt][r] + bias;
        const int m = mh * 32 + mt * 16 + g * 4 + r;
        if (RELU) {
          v = v > 0.f ? v : 0.f;
          *(__bf16*)(Hout + (uint32_t)m * HROWB +
                     (((uint32_t)(n * 2)) ^ (((uint32_t)m & 7u) << 4))) = (__bf16)v;
        } else if ((n & 1) == 0) {           // real component only
          const unsigned long long oi =
              (unsigned long long)m * (NCH * OUTS) + (unsigned long long)(n >> 1);
          if (oi < out_sz) Gout[oi] = v;
        }
      }
    }
  }
}

__global__ __launch_bounds__(BLOCK) void radiance_mlp_kernel(
    const float* __restrict__ ue,   const float* __restrict__ view,
    const float* __restrict__ feat, const int*   __restrict__ ids,
    const float* __restrict__ W1, const float* __restrict__ b1,
    const float* __restrict__ W2, const float* __restrict__ b2,
    const float* __restrict__ W3, const float* __restrict__ b3,
    float* __restrict__ out, unsigned long long out_sz)
{
  extern __shared__ __attribute__((aligned(16))) char smem[];
  char* buf0   = smem;               // h1: 32 KB (swizzled pitch 512B)
  char* buf1   = smem + 32768;       // x (pitch 336B) then h2: 32 KB
  char* wslots = smem + 65536;       // 4 x 16 KB W ring

  const int c    = blockIdx.x;       // one full-batch block per channel
  const int tid  = threadIdx.x;
  const int wave = tid >> 6;
  const int lane = tid & 63;

  // Stage input x -> bf16 in buf1 (pitch 336B), zero-pad k in [135,168).
  for (int idx = tid; idx < BATCH * (XPITCHB / 2); idx += BLOCK) {
    const int m = idx / (XPITCHB / 2);
    const int k = idx - m * (XPITCHB / 2);
    float v = 0.0f;
    if (k < 3)         v = ue[m * 3 + k];
    else if (k < 6)    v = view[m * 3 + (k - 3)];
    else if (k < 134)  v = feat[m * 128 + (k - 6)];
    else if (k == 134) v = ((float)ids[m] - 1.0f) * (1.0f / 63.0f);
    *(__bf16*)(buf1 + (uint32_t)m * XPITCHB + 2u * (uint32_t)k) = (__bf16)v;
  }
  __syncthreads();

  // L1: x(buf1) -> h1(buf0).  K=135 (5 k-tiles), N=256 in 2 chunks.
  const float* W1c = W1 + (size_t)c * IN_K * HID;
  const float* b1c = b1 + (size_t)c * HID;
  chunk_pipe<IN_K, 5, HID, 128, false, true>(buf1, W1c, b1c, buf0, nullptr, 0, 0,
                                             wslots, wave, lane);
  chunk_pipe<IN_K, 5, HID, 128, false, true>(buf1, W1c, b1c, buf0, nullptr, 0, 128,
                                             wslots, wave, lane);

  // L2: h1(buf0) -> h2(buf1).  K=256 (8 k-tiles), N=256 in 2 chunks.
  const float* W2c = W2 + (size_t)c * HID * HID;
  const float* b2c = b2 + (size_t)c * HID;
  chunk_pipe<HID, 8, HID, 128, true, true>(buf0, W2c, b2c, buf1, nullptr, 0, 0,
                                           wslots, wave, lane);
  chunk_pipe<HID, 8, HID, 128, true, true>(buf0, W2c, b2c, buf1, nullptr, 0, 128,
                                           wslots, wave, lane);

  // L3: h2(buf1) -> out.  K=256, N=816 = 6 x 128 + 48.
  const float* W3c = W3 + (size_t)c * HID * OUTN;
  const float* b3c = b3 + (size_t)c * OUTN;
  float* outc = out + (size_t)c * OUTS;
  for (int cc = 0; cc < 6; ++cc)
    chunk_pipe<HID, 8, OUTN, 128, true, false>(buf1, W3c, b3c, nullptr, outc,
                                               out_sz, cc * 128, wslots, wave, lane);
  chunk_pipe<HID, 8, OUTN, 48, true, false>(buf1, W3c, b3c, nullptr, outc,
                                            out_sz, 768, wslots, wave, lane);
}

extern "C" void kernel_launch(void* const* d_in, const int* in_sizes, int n_in,
                              void* d_out, int out_size, void* d_ws, size_t ws_size,
                              hipStream_t stream) {
  const float* ue   = (const float*)d_in[0];
  const float* view = (const float*)d_in[1];
  const float* feat = (const float*)d_in[2];
  const int*   ids  = (const int*)d_in[3];
  const float* W1   = (const float*)d_in[4];
  const float* b1   = (const float*)d_in[5];
  const float* W2   = (const float*)d_in[6];
  const float* b2   = (const float*)d_in[7];
  const float* W3   = (const float*)d_in[8];
  const float* b3   = (const float*)d_in[9];
  float* out = (float*)d_out;

  // Host-side attribute set (not a stream op; graph-capture-safe, idempotent).
  hipFuncSetAttribute(reinterpret_cast<const void*>(radiance_mlp_kernel),
                      hipFuncAttributeMaxDynamicSharedMemorySize, SMEM_BYTES);

  hipLaunchKernelGGL(radiance_mlp_kernel, dim3(NCH), dim3(BLOCK), SMEM_BYTES,
                     stream, ue, view, feat, ids, W1, b1, W2, b2, W3, b3,
                     out, (unsigned long long)out_size);
}